// Round 13
// baseline (125.119 us; speedup 1.0000x reference)
//
#include <hip/hip_runtime.h>
#include <hip/hip_bf16.h>
#include <math.h>

#define B_N   2000
#define T_N   32
#define CIN_N 32
#define COUT_N 128
#define E_N   32000
#define NEG_S 0.01f
#define EPS_S 1e-5f
#define NNODE (B_N * T_N)   // 64000
#define EPAD_N 46080        // padded CSR capacity (multiple-of-8 per node: E + 7*B rounded up)
// contiguous meta region: deg(2000)+cnt(2000)+cursor(2000)+offs(2004)+csr_src(46080)+csr_norm(46080)
#define META_I4 25041       // 100164 ints = 25041 int4

typedef __attribute__((ext_vector_type(8))) __bf16 bf16x8;
typedef __attribute__((ext_vector_type(4))) float f32x4;
typedef __attribute__((ext_vector_type(8))) unsigned short u16x8;

__device__ __forceinline__ unsigned short f2bf(float f) {
  unsigned u = __builtin_bit_cast(unsigned, f);
  u += 0x7FFFu + ((u >> 16) & 1u);   // RNE (finite values)
  return (unsigned short)(u >> 16);
}
__device__ __forceinline__ float bf2f(unsigned short h) {
  unsigned u = ((unsigned)h) << 16;
  return __builtin_bit_cast(float, u);
}

// ---------------- Kernel P: fused prep — zero meta + cast both weight tensors ----------------
__global__ __launch_bounds__(256) void k_prep(
    const float* __restrict__ cw, const float* __restrict__ tw,
    unsigned short* __restrict__ wBc, unsigned short* __restrict__ wB,
    int4* __restrict__ meta)
{
  const int tid0 = blockIdx.x * 256 + threadIdx.x;
  const int stride = gridDim.x * 256;
  const int4 z = {0, 0, 0, 0};
  for (int i = tid0; i < META_I4; i += stride) meta[i] = z;
  for (int idx = tid0; idx < 12288; idx += stride) {
    int e = idx & 7, lane = (idx >> 3) & 63, rest = idx >> 9;
    int ks = rest % 3, nf2 = rest / 3;
    int col = nf2 * 16 + (lane & 15);
    int k = ks * 32 + ((lane >> 4) << 3) + e;
    wBc[idx] = f2bf(cw[col * 96 + k]);
  }
  for (int idx = tid0; idx < 49152; idx += stride) {
    int e = idx & 7, lane = (idx >> 3) & 63, rest = idx >> 9;
    int ks = rest % 12, nf2 = rest / 12;
    int col = nf2 * 16 + (lane & 15);
    int k = ks * 32 + ((lane >> 4) << 3) + e;
    wB[idx] = f2bf(tw[(k >> 7) * 16384 + (k & 127) * 128 + col]);
  }
}

// ---------------- Kernel 1: FUSED causal-conv (MFMA) + bias + LeakyReLU + LayerNorm ----------
// Block = 4 samples x 2 waves; wave = 16 timesteps (t0=0/16) x 128 cols of one sample b.
__global__ __launch_bounds__(512, 4) void k_convln(
    const float* __restrict__ x, const unsigned short* __restrict__ wBc,
    const float* __restrict__ cb, const float* __restrict__ gamma,
    const float* __restrict__ beta, unsigned short* __restrict__ x0)
{
  __shared__ unsigned short sB[12288];   // 24KB conv weights, frag-order
  __shared__ float sx4[4][1088];         // 17KB: per-sample im2col source, sx4[s][ci*34+t+2]
  __shared__ float red1[8], red2[8];
  const int tid = threadIdx.x;
  const int w = tid >> 6, lane = tid & 63;
  const int s = w >> 1;                       // sample slot 0..3
  const int b = blockIdx.x * 4 + s;
  const int t0 = (w & 1) * 16;
  const int r = lane & 15, q = lane >> 4;

  #pragma unroll
  for (int i = 0; i < 3; ++i) {
    int id = i * 512 + tid;                   // 1536 float4
    ((float4*)sB)[id] = ((const float4*)wBc)[id];
  }
  for (int idx = tid; idx < 4 * 1088; idx += 512) {
    int ss = idx / 1088;
    int rem = idx - ss * 1088;
    int ci = rem / 34, tt = rem - ci * 34;
    sx4[ss][rem] = (tt >= 2) ? x[(blockIdx.x * 4 + ss) * 1024 + ci * 32 + (tt - 2)] : 0.f;
  }
  __syncthreads();

  const int ta = t0 + r;
  u16x8 a_[3];
  #pragma unroll
  for (int ks = 0; ks < 3; ++ks) {
    #pragma unroll
    for (int e = 0; e < 8; ++e) {
      int k = ks * 32 + q * 8 + e;
      int ci = k / 3, kk = k - ci * 3;
      a_[ks][e] = f2bf(sx4[s][ci * 34 + ta + kk]);
    }
  }

  f32x4 acc[8] = {};
  #pragma unroll
  for (int ks = 0; ks < 3; ++ks) {
    bf16x8 a = __builtin_bit_cast(bf16x8, a_[ks]);
    #pragma unroll
    for (int nf = 0; nf < 8; ++nf) {
      bf16x8 bv = *(const bf16x8*)&sB[((nf * 3 + ks) * 64 + lane) * 8];
      acc[nf] = __builtin_amdgcn_mfma_f32_16x16x32_bf16(a, bv, acc[nf], 0, 0, 0);
    }
  }

  float s1 = 0.f, s2 = 0.f;
  #pragma unroll
  for (int nf = 0; nf < 8; ++nf) {
    const float bias = cb[nf * 16 + r];
    #pragma unroll
    for (int i = 0; i < 4; ++i) {
      float u = acc[nf][i] + bias;
      u = (u >= 0.f) ? u : NEG_S * u;
      acc[nf][i] = u;
      s1 += u; s2 += u * u;
    }
  }
  #pragma unroll
  for (int d = 32; d > 0; d >>= 1) {
    s1 += __shfl_down(s1, d);
    s2 += __shfl_down(s2, d);
  }
  if (lane == 0) { red1[w] = s1; red2[w] = s2; }
  __syncthreads();
  const float a1 = red1[w & ~1] + red1[w | 1];
  const float a2 = red2[w & ~1] + red2[w | 1];
  const float mu = a1 / 4096.f;
  const float rs = rsqrtf(a2 / 4096.f - mu * mu + EPS_S);

  #pragma unroll
  for (int nf = 0; nf < 8; ++nf) {
    const int col = nf * 16 + r;
    #pragma unroll
    for (int i = 0; i < 4; ++i) {
      const int t = t0 + q * 4 + i;
      float v = (acc[nf][i] - mu) * rs * gamma[col * 32 + t] + beta[col * 32 + t];
      x0[((size_t)b * 32 + t) * 128 + col] = f2bf(v);
    }
  }
}

// ---------------- Kernel 2: in-degree (weighted) + in-edge counts ----------------
__global__ void k_deg(const int* __restrict__ ei, const float* __restrict__ ew,
                      float* __restrict__ deg, int* __restrict__ cnt)
{
  int e = blockIdx.x * 256 + threadIdx.x;
  if (e >= E_N) return;
  int d = ei[E_N + e];
  atomicAdd(&deg[d], ew[e]);
  atomicAdd(&cnt[d], 1);
}

// ---------------- Kernel 3: single-block exclusive scan over 2000 PADDED counts ----------------
// Pads each node's segment to a multiple of 8 for k_prop's 8-wide unroll.
__global__ __launch_bounds__(256) void k_scan(const int* __restrict__ cnt, int* __restrict__ offs)
{
  __shared__ int wsum[4];
  int tid = threadIdx.x;
  int vals[8];
  int run = 0;
  #pragma unroll
  for (int i = 0; i < 8; ++i) {
    int idx = tid * 8 + i;
    vals[i] = run;
    int v = (idx < B_N) ? cnt[idx] : 0;
    v = (v + 7) & ~7;                       // pad to multiple of 8
    run += v;
  }
  int lane = tid & 63, wid = tid >> 6;
  int xs = run;
  #pragma unroll
  for (int d = 1; d < 64; d <<= 1) {
    int y = __shfl_up(xs, d);
    if (lane >= d) xs += y;
  }
  if (lane == 63) wsum[wid] = xs;
  __syncthreads();
  int pre = 0;
  for (int w = 0; w < wid; ++w) pre += wsum[w];
  int excl = pre + xs - run;
  #pragma unroll
  for (int i = 0; i < 8; ++i) {
    int idx = tid * 8 + i;
    if (idx <= B_N) offs[idx] = excl + vals[i];
  }
}

// ---------------- Kernel 4: CSR scatter + edge norm (pad slots stay {src=0, norm=0}) ----------------
__global__ void k_scatter(const int* __restrict__ ei, const float* __restrict__ ew,
                          const float* __restrict__ deg, const int* __restrict__ offs,
                          int* __restrict__ cursor, int* __restrict__ csr_src,
                          float* __restrict__ csr_norm)
{
  int e = blockIdx.x * 256 + threadIdx.x;
  if (e >= E_N) return;
  int s = ei[e], d = ei[E_N + e];
  float ds_ = deg[s], dd = deg[d];
  float dis_s = (ds_ > 0.f) ? rsqrtf(fmaxf(ds_, 1e-12f)) : 0.f;
  float dis_d = (dd  > 0.f) ? rsqrtf(fmaxf(dd,  1e-12f)) : 0.f;
  float nrm = dis_s * ew[e] * dis_d;
  int pos = offs[d] + atomicAdd(&cursor[d], 1);
  csr_src[pos] = s;
  csr_norm[pos] = nrm;
}

// ---------------- Kernel 5: one-hop propagation, b-major, 8-wide edge unroll ----------------
// Wave = (dst b, t-quarter tq): per edge one b128/lane from hin[src][tq*4..+4][128] (1KB contig).
// 8 independent gathers in flight per iteration (latency-bound fix; r12's 4-wide was flat).
__global__ __launch_bounds__(256) void k_prop(
    const unsigned short* __restrict__ hin, unsigned short* __restrict__ hout,
    const int* __restrict__ offs, const int* __restrict__ csr_src,
    const float* __restrict__ csr_norm)
{
  int gw = (blockIdx.x * 256 + threadIdx.x) >> 6;
  int lane = threadIdx.x & 63;
  if (gw >= B_N * 8) return;
  int tq = gw / B_N;                 // 0..7
  int b  = gw - tq * B_N;
  int beg = offs[b], end = offs[b + 1];           // both multiples of 8
  const size_t lelem = (size_t)(tq * 4 + (lane >> 4)) * 128 + (lane & 15) * 8;
  float acc[8] = {};
  for (int i = beg; i < end; i += 8) {
    int4   sa = *(const int4*)&csr_src[i];
    int4   sb = *(const int4*)&csr_src[i + 4];
    float4 na = *(const float4*)&csr_norm[i];
    float4 nb = *(const float4*)&csr_norm[i + 4];
    u16x8 v0 = *(const u16x8*)&hin[(size_t)sa.x * 4096 + lelem];
    u16x8 v1 = *(const u16x8*)&hin[(size_t)sa.y * 4096 + lelem];
    u16x8 v2 = *(const u16x8*)&hin[(size_t)sa.z * 4096 + lelem];
    u16x8 v3 = *(const u16x8*)&hin[(size_t)sa.w * 4096 + lelem];
    u16x8 v4 = *(const u16x8*)&hin[(size_t)sb.x * 4096 + lelem];
    u16x8 v5 = *(const u16x8*)&hin[(size_t)sb.y * 4096 + lelem];
    u16x8 v6 = *(const u16x8*)&hin[(size_t)sb.z * 4096 + lelem];
    u16x8 v7 = *(const u16x8*)&hin[(size_t)sb.w * 4096 + lelem];
    #pragma unroll
    for (int e = 0; e < 8; ++e) {
      float p0 = na.x * bf2f(v0[e]) + na.y * bf2f(v1[e]);
      float p1 = na.z * bf2f(v2[e]) + na.w * bf2f(v3[e]);
      float p2 = nb.x * bf2f(v4[e]) + nb.y * bf2f(v5[e]);
      float p3 = nb.z * bf2f(v6[e]) + nb.w * bf2f(v7[e]);
      acc[e] += (p0 + p1) + (p2 + p3);
    }
  }
  u16x8 o;
  #pragma unroll
  for (int e = 0; e < 8; ++e) o[e] = f2bf(acc[e]);
  *(u16x8*)&hout[(size_t)b * 4096 + lelem] = o;
}

// ---------------- Kernel 6: MFMA triple-GEMM (K=384) + epilogue, direct [b][c][t] store ---------
// Block = 8 b's x full 32 t x 64 cols (chalf); sB staged ONCE, both t-halves computed serially.
// Grid 500 = 250 b-octs x 2 chalf.
__global__ __launch_bounds__(512, 4) void k_gemm(
    const unsigned short* __restrict__ x0, const unsigned short* __restrict__ h1,
    const unsigned short* __restrict__ h2, const unsigned short* __restrict__ wB,
    const float* __restrict__ tb, float* __restrict__ out)
{
  __shared__ unsigned short sB[24576];   // 48KB: 64 cols x 384 K, fragment-ordered
  const int tid = threadIdx.x;
  const int w = tid >> 6, lane = tid & 63;
  const int chalf = blockIdx.x / 250;
  const int b = (blockIdx.x % 250) * 8 + w;
  const int r = lane & 15, q = lane >> 4;

  const float4* gB = (const float4*)(wB + (size_t)chalf * 24576);
  #pragma unroll
  for (int i = 0; i < 6; ++i) {
    int id = i * 512 + tid;
    ((float4*)sB)[id] = gB[id];
  }
  __syncthreads();

  #pragma unroll
  for (int thalf = 0; thalf < 2; ++thalf) {
    const int t0 = thalf * 16;
    const size_t abase = ((size_t)b * 32 + t0 + r) * 128 + q * 8;
    bf16x8 a[12];
    #pragma unroll
    for (int ks = 0; ks < 12; ++ks) {
      const unsigned short* arr = (ks < 4) ? x0 : (ks < 8) ? h1 : h2;
      a[ks] = *(const bf16x8*)&arr[abase + (size_t)(ks & 3) * 32];
    }

    f32x4 acc[4] = {};
    #pragma unroll
    for (int ks = 0; ks < 12; ++ks) {
      #pragma unroll
      for (int nf = 0; nf < 4; ++nf) {
        bf16x8 bv = *(const bf16x8*)&sB[((nf * 12 + ks) * 64 + lane) * 8];
        acc[nf] = __builtin_amdgcn_mfma_f32_16x16x32_bf16(a[ks], bv, acc[nf], 0, 0, 0);
      }
    }

    #pragma unroll
    for (int nf = 0; nf < 4; ++nf) {
      const int col = chalf * 64 + nf * 16 + r;
      const float bias = tb[col];
      float4 o;
      #pragma unroll
      for (int i = 0; i < 4; ++i) {
        const int t = t0 + q * 4 + i;
        float u = acc[nf][i] + bias;
        u = (u >= 0.f) ? u : NEG_S * u;
        float xv = bf2f(x0[((size_t)b * 32 + t) * 128 + col]);   // residual = xp
        ((float*)&o)[i] = xv + u;
      }
      *(float4*)&out[(size_t)b * 4096 + col * 32 + t0 + q * 4] = o;
    }
  }
}

extern "C" void kernel_launch(void* const* d_in, const int* in_sizes, int n_in,
                              void* d_out, int out_size, void* d_ws, size_t ws_size,
                              hipStream_t stream)
{
  const float* x     = (const float*)d_in[0];
  const int*   ei    = (const int*)d_in[1];
  const float* ew    = (const float*)d_in[2];
  const float* cw    = (const float*)d_in[3];
  const float* cb    = (const float*)d_in[4];
  const float* gamma = (const float*)d_in[5];
  const float* beta  = (const float*)d_in[6];
  const float* tw    = (const float*)d_in[7];
  const float* tb    = (const float*)d_in[8];
  float* out = (float*)d_out;

  // workspace layout: three b-major feature arrays [b][32][128] bf16
  unsigned short* x0 = (unsigned short*)d_ws;                   // 64000*128 bf16
  unsigned short* h1 = x0 + (size_t)NNODE * 128;                // 64000*128 bf16
  unsigned short* h2 = h1 + (size_t)NNODE * 128;                // 64000*128 bf16
  float* deg = (float*)(h2 + (size_t)NNODE * 128);              // 2000 (16B aligned)
  int*   cnt    = (int*)(deg + B_N);                            // 2000
  int*   cursor = cnt + B_N;                                    // 2000
  int*   offs   = cursor + B_N;                                 // 2004 (padded for 16B align)
  int*   csr_src = offs + (B_N + 4);                            // EPAD_N
  float* csr_norm = (float*)(csr_src + EPAD_N);                 // EPAD_N
  unsigned short* wBc = (unsigned short*)(csr_norm + EPAD_N);   // 12288 bf16 frag-order
  unsigned short* wB  = wBc + 12288;                            // 49152 bf16 frag-order

  k_prep<<<96, 256, 0, stream>>>(cw, tw, wBc, wB, (int4*)deg);
  k_convln<<<500, 512, 0, stream>>>(x, wBc, cb, gamma, beta, x0);
  k_deg<<<(E_N + 255) / 256, 256, 0, stream>>>(ei, ew, deg, cnt);
  k_scan<<<1, 256, 0, stream>>>(cnt, offs);
  k_scatter<<<(E_N + 255) / 256, 256, 0, stream>>>(ei, ew, deg, offs, cursor, csr_src, csr_norm);
  k_prop<<<B_N * 8 / 4, 256, 0, stream>>>(x0, h1, offs, csr_src, csr_norm);
  k_prop<<<B_N * 8 / 4, 256, 0, stream>>>(h1, h2, offs, csr_src, csr_norm);
  k_gemm<<<500, 512, 0, stream>>>(x0, h1, h2, wB, tb, out);
}

// Round 14
// 106.972 us; speedup vs baseline: 1.1696x; 1.1696x over previous
//
#include <hip/hip_runtime.h>
#include <hip/hip_bf16.h>
#include <math.h>

#define B_N   2000
#define T_N   32
#define CIN_N 32
#define COUT_N 128
#define E_N   32000
#define NEG_S 0.01f
#define EPS_S 1e-5f
#define NNODE (B_N * T_N)   // 64000
#define EPAD_N 38016        // padded CSR capacity (multiple-of-4 per node)
// contiguous meta region: deg(2000)+cnt(2000)+cursor(2000)+offs(2004)+csr_src(38016)+csr_norm(38016)
#define META_I4 21009       // 84036 ints = 21009 int4

typedef __attribute__((ext_vector_type(8))) __bf16 bf16x8;
typedef __attribute__((ext_vector_type(4))) float f32x4;
typedef __attribute__((ext_vector_type(8))) unsigned short u16x8;

__device__ __forceinline__ unsigned short f2bf(float f) {
  unsigned u = __builtin_bit_cast(unsigned, f);
  u += 0x7FFFu + ((u >> 16) & 1u);   // RNE (finite values)
  return (unsigned short)(u >> 16);
}
__device__ __forceinline__ float bf2f(unsigned short h) {
  unsigned u = ((unsigned)h) << 16;
  return __builtin_bit_cast(float, u);
}

// ---------------- Kernel P: fused prep — zero meta + cast both weight tensors ----------------
__global__ __launch_bounds__(256) void k_prep(
    const float* __restrict__ cw, const float* __restrict__ tw,
    unsigned short* __restrict__ wBc, unsigned short* __restrict__ wB,
    int4* __restrict__ meta)
{
  const int tid0 = blockIdx.x * 256 + threadIdx.x;
  const int stride = gridDim.x * 256;
  const int4 z = {0, 0, 0, 0};
  for (int i = tid0; i < META_I4; i += stride) meta[i] = z;
  for (int idx = tid0; idx < 12288; idx += stride) {
    int e = idx & 7, lane = (idx >> 3) & 63, rest = idx >> 9;
    int ks = rest % 3, nf2 = rest / 3;
    int col = nf2 * 16 + (lane & 15);
    int k = ks * 32 + ((lane >> 4) << 3) + e;
    wBc[idx] = f2bf(cw[col * 96 + k]);
  }
  for (int idx = tid0; idx < 49152; idx += stride) {
    int e = idx & 7, lane = (idx >> 3) & 63, rest = idx >> 9;
    int ks = rest % 12, nf2 = rest / 12;
    int col = nf2 * 16 + (lane & 15);
    int k = ks * 32 + ((lane >> 4) << 3) + e;
    wB[idx] = f2bf(tw[(k >> 7) * 16384 + (k & 127) * 128 + col]);
  }
}

// ---------------- Kernel 1: FUSED causal-conv (MFMA) + bias + LeakyReLU + LayerNorm ----------
// Block = 4 samples x 2 waves; wave = 16 timesteps (t0=0/16) x 128 cols of one sample b.
__global__ __launch_bounds__(512, 4) void k_convln(
    const float* __restrict__ x, const unsigned short* __restrict__ wBc,
    const float* __restrict__ cb, const float* __restrict__ gamma,
    const float* __restrict__ beta, unsigned short* __restrict__ x0)
{
  __shared__ unsigned short sB[12288];   // 24KB conv weights, frag-order
  __shared__ float sx4[4][1088];         // 17KB: per-sample im2col source, sx4[s][ci*34+t+2]
  __shared__ float red1[8], red2[8];
  const int tid = threadIdx.x;
  const int w = tid >> 6, lane = tid & 63;
  const int s = w >> 1;                       // sample slot 0..3
  const int b = blockIdx.x * 4 + s;
  const int t0 = (w & 1) * 16;
  const int r = lane & 15, q = lane >> 4;

  #pragma unroll
  for (int i = 0; i < 3; ++i) {
    int id = i * 512 + tid;                   // 1536 float4
    ((float4*)sB)[id] = ((const float4*)wBc)[id];
  }
  for (int idx = tid; idx < 4 * 1088; idx += 512) {
    int ss = idx / 1088;
    int rem = idx - ss * 1088;
    int ci = rem / 34, tt = rem - ci * 34;
    sx4[ss][rem] = (tt >= 2) ? x[(blockIdx.x * 4 + ss) * 1024 + ci * 32 + (tt - 2)] : 0.f;
  }
  __syncthreads();

  const int ta = t0 + r;
  u16x8 a_[3];
  #pragma unroll
  for (int ks = 0; ks < 3; ++ks) {
    #pragma unroll
    for (int e = 0; e < 8; ++e) {
      int k = ks * 32 + q * 8 + e;
      int ci = k / 3, kk = k - ci * 3;
      a_[ks][e] = f2bf(sx4[s][ci * 34 + ta + kk]);
    }
  }

  f32x4 acc[8] = {};
  #pragma unroll
  for (int ks = 0; ks < 3; ++ks) {
    bf16x8 a = __builtin_bit_cast(bf16x8, a_[ks]);
    #pragma unroll
    for (int nf = 0; nf < 8; ++nf) {
      bf16x8 bv = *(const bf16x8*)&sB[((nf * 3 + ks) * 64 + lane) * 8];
      acc[nf] = __builtin_amdgcn_mfma_f32_16x16x32_bf16(a, bv, acc[nf], 0, 0, 0);
    }
  }

  float s1 = 0.f, s2 = 0.f;
  #pragma unroll
  for (int nf = 0; nf < 8; ++nf) {
    const float bias = cb[nf * 16 + r];
    #pragma unroll
    for (int i = 0; i < 4; ++i) {
      float u = acc[nf][i] + bias;
      u = (u >= 0.f) ? u : NEG_S * u;
      acc[nf][i] = u;
      s1 += u; s2 += u * u;
    }
  }
  #pragma unroll
  for (int d = 32; d > 0; d >>= 1) {
    s1 += __shfl_down(s1, d);
    s2 += __shfl_down(s2, d);
  }
  if (lane == 0) { red1[w] = s1; red2[w] = s2; }
  __syncthreads();
  const float a1 = red1[w & ~1] + red1[w | 1];
  const float a2 = red2[w & ~1] + red2[w | 1];
  const float mu = a1 / 4096.f;
  const float rs = rsqrtf(a2 / 4096.f - mu * mu + EPS_S);

  #pragma unroll
  for (int nf = 0; nf < 8; ++nf) {
    const int col = nf * 16 + r;
    #pragma unroll
    for (int i = 0; i < 4; ++i) {
      const int t = t0 + q * 4 + i;
      float v = (acc[nf][i] - mu) * rs * gamma[col * 32 + t] + beta[col * 32 + t];
      x0[((size_t)b * 32 + t) * 128 + col] = f2bf(v);
    }
  }
}

// ---------------- Kernel 2: in-degree (weighted) + in-edge counts ----------------
__global__ void k_deg(const int* __restrict__ ei, const float* __restrict__ ew,
                      float* __restrict__ deg, int* __restrict__ cnt)
{
  int e = blockIdx.x * 256 + threadIdx.x;
  if (e >= E_N) return;
  int d = ei[E_N + e];
  atomicAdd(&deg[d], ew[e]);
  atomicAdd(&cnt[d], 1);
}

// ---------------- Kernel 3: single-block exclusive scan over 2000 PADDED counts ----------------
__global__ __launch_bounds__(256) void k_scan(const int* __restrict__ cnt, int* __restrict__ offs)
{
  __shared__ int wsum[4];
  int tid = threadIdx.x;
  int vals[8];
  int run = 0;
  #pragma unroll
  for (int i = 0; i < 8; ++i) {
    int idx = tid * 8 + i;
    vals[i] = run;
    int v = (idx < B_N) ? cnt[idx] : 0;
    v = (v + 3) & ~3;                       // pad to multiple of 4
    run += v;
  }
  int lane = tid & 63, wid = tid >> 6;
  int xs = run;
  #pragma unroll
  for (int d = 1; d < 64; d <<= 1) {
    int y = __shfl_up(xs, d);
    if (lane >= d) xs += y;
  }
  if (lane == 63) wsum[wid] = xs;
  __syncthreads();
  int pre = 0;
  for (int w = 0; w < wid; ++w) pre += wsum[w];
  int excl = pre + xs - run;
  #pragma unroll
  for (int i = 0; i < 8; ++i) {
    int idx = tid * 8 + i;
    if (idx <= B_N) offs[idx] = excl + vals[i];
  }
}

// ---------------- Kernel 4: CSR scatter + edge norm (pad slots stay {src=0, norm=0}) ----------------
__global__ void k_scatter(const int* __restrict__ ei, const float* __restrict__ ew,
                          const float* __restrict__ deg, const int* __restrict__ offs,
                          int* __restrict__ cursor, int* __restrict__ csr_src,
                          float* __restrict__ csr_norm)
{
  int e = blockIdx.x * 256 + threadIdx.x;
  if (e >= E_N) return;
  int s = ei[e], d = ei[E_N + e];
  float ds_ = deg[s], dd = deg[d];
  float dis_s = (ds_ > 0.f) ? rsqrtf(fmaxf(ds_, 1e-12f)) : 0.f;
  float dis_d = (dd  > 0.f) ? rsqrtf(fmaxf(dd,  1e-12f)) : 0.f;
  float nrm = dis_s * ew[e] * dis_d;
  int pos = offs[d] + atomicAdd(&cursor[d], 1);
  csr_src[pos] = s;
  csr_norm[pos] = nrm;
}

// ---------------- Kernel 5: one-hop propagation, b-major, XCD-locality mapping ----------------
// tq = blockIdx.x % 8 so (round-robin dispatch) XCD k serves ONLY the 1MB band tq=k -> L2-resident.
// Wave = (dst b, tq): per edge one b128/lane from hin[src][tq*4..+4][128] (1KB contiguous).
// Grid 4000 = 8 tq x 500 bgroups x 4 waves. Lane: t=tq*4+(l>>4), c=(l&15)*8.
__global__ __launch_bounds__(256) void k_prop(
    const unsigned short* __restrict__ hin, unsigned short* __restrict__ hout,
    const int* __restrict__ offs, const int* __restrict__ csr_src,
    const float* __restrict__ csr_norm)
{
  const int bid = blockIdx.x;
  const int tq = bid & 7;                    // XCD-aligned t-quarter
  const int bgroup = bid >> 3;               // 0..499
  const int widx = threadIdx.x >> 6;
  const int lane = threadIdx.x & 63;
  const int b = bgroup * 4 + widx;           // 0..1999
  int beg = offs[b], end = offs[b + 1];      // both multiples of 4
  const size_t lelem = (size_t)(tq * 4 + (lane >> 4)) * 128 + (lane & 15) * 8;
  float acc[8] = {};
  for (int i = beg; i < end; i += 4) {
    int4   s4 = *(const int4*)&csr_src[i];
    float4 n4 = *(const float4*)&csr_norm[i];
    u16x8 v0 = *(const u16x8*)&hin[(size_t)s4.x * 4096 + lelem];
    u16x8 v1 = *(const u16x8*)&hin[(size_t)s4.y * 4096 + lelem];
    u16x8 v2 = *(const u16x8*)&hin[(size_t)s4.z * 4096 + lelem];
    u16x8 v3 = *(const u16x8*)&hin[(size_t)s4.w * 4096 + lelem];
    #pragma unroll
    for (int e = 0; e < 8; ++e) {
      acc[e] += n4.x * bf2f(v0[e]) + n4.y * bf2f(v1[e])
              + n4.z * bf2f(v2[e]) + n4.w * bf2f(v3[e]);
    }
  }
  u16x8 o;
  #pragma unroll
  for (int e = 0; e < 8; ++e) o[e] = f2bf(acc[e]);
  *(u16x8*)&hout[(size_t)b * 4096 + lelem] = o;
}

// ---------------- Kernel 6: MFMA triple-GEMM (K=384) + epilogue, direct [b][c][t] store ---------
// Wave M-tile = 16 timesteps of ONE sample b; A-frags from x0/h1/h2 (4 each); cols 64 per chalf.
// Grid 1000 = 250 b-octs x {thalf, chalf}  (r12-proven version).
__global__ __launch_bounds__(512, 4) void k_gemm(
    const unsigned short* __restrict__ x0, const unsigned short* __restrict__ h1,
    const unsigned short* __restrict__ h2, const unsigned short* __restrict__ wB,
    const float* __restrict__ tb, float* __restrict__ out)
{
  __shared__ unsigned short sB[24576];   // 48KB: 64 cols x 384 K, fragment-ordered
  const int tid = threadIdx.x;
  const int w = tid >> 6, lane = tid & 63;
  const int sel = blockIdx.x / 250;                  // 0..3
  const int b = (blockIdx.x % 250) * 8 + w;
  const int thalf = sel & 1, chalf = sel >> 1;
  const int t0 = thalf * 16;
  const int r = lane & 15, q = lane >> 4;

  const size_t abase = ((size_t)b * 32 + t0 + r) * 128 + q * 8;
  bf16x8 a[12];
  #pragma unroll
  for (int ks = 0; ks < 12; ++ks) {
    const unsigned short* arr = (ks < 4) ? x0 : (ks < 8) ? h1 : h2;
    a[ks] = *(const bf16x8*)&arr[abase + (size_t)(ks & 3) * 32];
  }

  const float4* gB = (const float4*)(wB + (size_t)chalf * 24576);
  #pragma unroll
  for (int i = 0; i < 6; ++i) {
    int id = i * 512 + tid;
    ((float4*)sB)[id] = gB[id];
  }
  __syncthreads();

  f32x4 acc[4] = {};
  #pragma unroll
  for (int ks = 0; ks < 12; ++ks) {
    #pragma unroll
    for (int nf = 0; nf < 4; ++nf) {
      bf16x8 bv = *(const bf16x8*)&sB[((nf * 12 + ks) * 64 + lane) * 8];
      acc[nf] = __builtin_amdgcn_mfma_f32_16x16x32_bf16(a[ks], bv, acc[nf], 0, 0, 0);
    }
  }

  #pragma unroll
  for (int nf = 0; nf < 4; ++nf) {
    const int col = chalf * 64 + nf * 16 + r;
    const float bias = tb[col];
    float4 o;
    #pragma unroll
    for (int i = 0; i < 4; ++i) {
      const int t = t0 + q * 4 + i;
      float u = acc[nf][i] + bias;
      u = (u >= 0.f) ? u : NEG_S * u;
      float xv = bf2f(x0[((size_t)b * 32 + t) * 128 + col]);   // residual = xp
      ((float*)&o)[i] = xv + u;
    }
    *(float4*)&out[(size_t)b * 4096 + col * 32 + t0 + q * 4] = o;
  }
}

extern "C" void kernel_launch(void* const* d_in, const int* in_sizes, int n_in,
                              void* d_out, int out_size, void* d_ws, size_t ws_size,
                              hipStream_t stream)
{
  const float* x     = (const float*)d_in[0];
  const int*   ei    = (const int*)d_in[1];
  const float* ew    = (const float*)d_in[2];
  const float* cw    = (const float*)d_in[3];
  const float* cb    = (const float*)d_in[4];
  const float* gamma = (const float*)d_in[5];
  const float* beta  = (const float*)d_in[6];
  const float* tw    = (const float*)d_in[7];
  const float* tb    = (const float*)d_in[8];
  float* out = (float*)d_out;

  // workspace layout: three b-major feature arrays [b][32][128] bf16
  unsigned short* x0 = (unsigned short*)d_ws;                   // 64000*128 bf16
  unsigned short* h1 = x0 + (size_t)NNODE * 128;                // 64000*128 bf16
  unsigned short* h2 = h1 + (size_t)NNODE * 128;                // 64000*128 bf16
  float* deg = (float*)(h2 + (size_t)NNODE * 128);              // 2000 (16B aligned)
  int*   cnt    = (int*)(deg + B_N);                            // 2000
  int*   cursor = cnt + B_N;                                    // 2000
  int*   offs   = cursor + B_N;                                 // 2004 (padded for 16B align)
  int*   csr_src = offs + (B_N + 4);                            // EPAD_N
  float* csr_norm = (float*)(csr_src + EPAD_N);                 // EPAD_N
  unsigned short* wBc = (unsigned short*)(csr_norm + EPAD_N);   // 12288 bf16 frag-order
  unsigned short* wB  = wBc + 12288;                            // 49152 bf16 frag-order

  k_prep<<<96, 256, 0, stream>>>(cw, tw, wBc, wB, (int4*)deg);
  k_convln<<<500, 512, 0, stream>>>(x, wBc, cb, gamma, beta, x0);
  k_deg<<<(E_N + 255) / 256, 256, 0, stream>>>(ei, ew, deg, cnt);
  k_scan<<<1, 256, 0, stream>>>(cnt, offs);
  k_scatter<<<(E_N + 255) / 256, 256, 0, stream>>>(ei, ew, deg, offs, cursor, csr_src, csr_norm);
  k_prop<<<4000, 256, 0, stream>>>(x0, h1, offs, csr_src, csr_norm);
  k_prop<<<4000, 256, 0, stream>>>(h1, h2, offs, csr_src, csr_norm);
  k_gemm<<<1000, 512, 0, stream>>>(x0, h1, h2, wB, tb, out);
}

// Round 15
// 106.775 us; speedup vs baseline: 1.1718x; 1.0018x over previous
//
#include <hip/hip_runtime.h>
#include <hip/hip_bf16.h>
#include <math.h>

#define B_N   2000
#define T_N   32
#define CIN_N 32
#define COUT_N 128
#define E_N   32000
#define NEG_S 0.01f
#define EPS_S 1e-5f
#define NNODE (B_N * T_N)   // 64000
#define EPAD_N 38016        // padded CSR capacity (multiple-of-4 per node)
// contiguous meta region: deg(2000)+cnt(2000)+cursor(2000)+offs(2004)+csr_src(38016)+csr_norm(38016)
#define META_I4 21009       // 84036 ints = 21009 int4

typedef __attribute__((ext_vector_type(8))) __bf16 bf16x8;
typedef __attribute__((ext_vector_type(4))) float f32x4;
typedef __attribute__((ext_vector_type(2))) float f32x2;
typedef __attribute__((ext_vector_type(8))) unsigned short u16x8;

__device__ __forceinline__ unsigned short f2bf(float f) {
  unsigned u = __builtin_bit_cast(unsigned, f);
  u += 0x7FFFu + ((u >> 16) & 1u);   // RNE (finite values)
  return (unsigned short)(u >> 16);
}
__device__ __forceinline__ float bf2f(unsigned short h) {
  unsigned u = ((unsigned)h) << 16;
  return __builtin_bit_cast(float, u);
}

// ---------------- Kernel P: fused prep — zero meta + cast both weight tensors ----------------
__global__ __launch_bounds__(256) void k_prep(
    const float* __restrict__ cw, const float* __restrict__ tw,
    unsigned short* __restrict__ wBc, unsigned short* __restrict__ wB,
    int4* __restrict__ meta)
{
  const int tid0 = blockIdx.x * 256 + threadIdx.x;
  const int stride = gridDim.x * 256;
  const int4 z = {0, 0, 0, 0};
  for (int i = tid0; i < META_I4; i += stride) meta[i] = z;
  for (int idx = tid0; idx < 12288; idx += stride) {
    int e = idx & 7, lane = (idx >> 3) & 63, rest = idx >> 9;
    int ks = rest % 3, nf2 = rest / 3;
    int col = nf2 * 16 + (lane & 15);
    int k = ks * 32 + ((lane >> 4) << 3) + e;
    wBc[idx] = f2bf(cw[col * 96 + k]);
  }
  for (int idx = tid0; idx < 49152; idx += stride) {
    int e = idx & 7, lane = (idx >> 3) & 63, rest = idx >> 9;
    int ks = rest % 12, nf2 = rest / 12;
    int col = nf2 * 16 + (lane & 15);
    int k = ks * 32 + ((lane >> 4) << 3) + e;
    wB[idx] = f2bf(tw[(k >> 7) * 16384 + (k & 127) * 128 + col]);
  }
}

// ---------------- Kernel 1: FUSED causal-conv (MFMA) + bias + LeakyReLU + LayerNorm ----------
// Block = 4 samples x 2 waves; wave = 16 timesteps (t0=0/16) x 128 cols of one sample b.
__global__ __launch_bounds__(512, 4) void k_convln(
    const float* __restrict__ x, const unsigned short* __restrict__ wBc,
    const float* __restrict__ cb, const float* __restrict__ gamma,
    const float* __restrict__ beta, unsigned short* __restrict__ x0)
{
  __shared__ unsigned short sB[12288];   // 24KB conv weights, frag-order
  __shared__ float sx4[4][1088];         // 17KB: per-sample im2col source, sx4[s][ci*34+t+2]
  __shared__ float red1[8], red2[8];
  const int tid = threadIdx.x;
  const int w = tid >> 6, lane = tid & 63;
  const int s = w >> 1;                       // sample slot 0..3
  const int b = blockIdx.x * 4 + s;
  const int t0 = (w & 1) * 16;
  const int r = lane & 15, q = lane >> 4;

  #pragma unroll
  for (int i = 0; i < 3; ++i) {
    int id = i * 512 + tid;                   // 1536 float4
    ((float4*)sB)[id] = ((const float4*)wBc)[id];
  }
  for (int idx = tid; idx < 4 * 1088; idx += 512) {
    int ss = idx / 1088;
    int rem = idx - ss * 1088;
    int ci = rem / 34, tt = rem - ci * 34;
    sx4[ss][rem] = (tt >= 2) ? x[(blockIdx.x * 4 + ss) * 1024 + ci * 32 + (tt - 2)] : 0.f;
  }
  __syncthreads();

  const int ta = t0 + r;
  u16x8 a_[3];
  #pragma unroll
  for (int ks = 0; ks < 3; ++ks) {
    #pragma unroll
    for (int e = 0; e < 8; ++e) {
      int k = ks * 32 + q * 8 + e;
      int ci = k / 3, kk = k - ci * 3;
      a_[ks][e] = f2bf(sx4[s][ci * 34 + ta + kk]);
    }
  }

  f32x4 acc[8] = {};
  #pragma unroll
  for (int ks = 0; ks < 3; ++ks) {
    bf16x8 a = __builtin_bit_cast(bf16x8, a_[ks]);
    #pragma unroll
    for (int nf = 0; nf < 8; ++nf) {
      bf16x8 bv = *(const bf16x8*)&sB[((nf * 3 + ks) * 64 + lane) * 8];
      acc[nf] = __builtin_amdgcn_mfma_f32_16x16x32_bf16(a, bv, acc[nf], 0, 0, 0);
    }
  }

  float s1 = 0.f, s2 = 0.f;
  #pragma unroll
  for (int nf = 0; nf < 8; ++nf) {
    const float bias = cb[nf * 16 + r];
    #pragma unroll
    for (int i = 0; i < 4; ++i) {
      float u = acc[nf][i] + bias;
      u = (u >= 0.f) ? u : NEG_S * u;
      acc[nf][i] = u;
      s1 += u; s2 += u * u;
    }
  }
  #pragma unroll
  for (int d = 32; d > 0; d >>= 1) {
    s1 += __shfl_down(s1, d);
    s2 += __shfl_down(s2, d);
  }
  if (lane == 0) { red1[w] = s1; red2[w] = s2; }
  __syncthreads();
  const float a1 = red1[w & ~1] + red1[w | 1];
  const float a2 = red2[w & ~1] + red2[w | 1];
  const float mu = a1 / 4096.f;
  const float rs = rsqrtf(a2 / 4096.f - mu * mu + EPS_S);

  #pragma unroll
  for (int nf = 0; nf < 8; ++nf) {
    const int col = nf * 16 + r;
    #pragma unroll
    for (int i = 0; i < 4; ++i) {
      const int t = t0 + q * 4 + i;
      float v = (acc[nf][i] - mu) * rs * gamma[col * 32 + t] + beta[col * 32 + t];
      x0[((size_t)b * 32 + t) * 128 + col] = f2bf(v);
    }
  }
}

// ---------------- Kernel 2: in-degree (weighted) + in-edge counts ----------------
__global__ void k_deg(const int* __restrict__ ei, const float* __restrict__ ew,
                      float* __restrict__ deg, int* __restrict__ cnt)
{
  int e = blockIdx.x * 256 + threadIdx.x;
  if (e >= E_N) return;
  int d = ei[E_N + e];
  atomicAdd(&deg[d], ew[e]);
  atomicAdd(&cnt[d], 1);
}

// ---------------- Kernel 3: single-block exclusive scan over 2000 PADDED counts ----------------
__global__ __launch_bounds__(256) void k_scan(const int* __restrict__ cnt, int* __restrict__ offs)
{
  __shared__ int wsum[4];
  int tid = threadIdx.x;
  int vals[8];
  int run = 0;
  #pragma unroll
  for (int i = 0; i < 8; ++i) {
    int idx = tid * 8 + i;
    vals[i] = run;
    int v = (idx < B_N) ? cnt[idx] : 0;
    v = (v + 3) & ~3;                       // pad to multiple of 4
    run += v;
  }
  int lane = tid & 63, wid = tid >> 6;
  int xs = run;
  #pragma unroll
  for (int d = 1; d < 64; d <<= 1) {
    int y = __shfl_up(xs, d);
    if (lane >= d) xs += y;
  }
  if (lane == 63) wsum[wid] = xs;
  __syncthreads();
  int pre = 0;
  for (int w = 0; w < wid; ++w) pre += wsum[w];
  int excl = pre + xs - run;
  #pragma unroll
  for (int i = 0; i < 8; ++i) {
    int idx = tid * 8 + i;
    if (idx <= B_N) offs[idx] = excl + vals[i];
  }
}

// ---------------- Kernel 4: CSR scatter + edge norm (pad slots stay {src=0, norm=0}) ----------------
__global__ void k_scatter(const int* __restrict__ ei, const float* __restrict__ ew,
                          const float* __restrict__ deg, const int* __restrict__ offs,
                          int* __restrict__ cursor, int* __restrict__ csr_src,
                          float* __restrict__ csr_norm)
{
  int e = blockIdx.x * 256 + threadIdx.x;
  if (e >= E_N) return;
  int s = ei[e], d = ei[E_N + e];
  float ds_ = deg[s], dd = deg[d];
  float dis_s = (ds_ > 0.f) ? rsqrtf(fmaxf(ds_, 1e-12f)) : 0.f;
  float dis_d = (dd  > 0.f) ? rsqrtf(fmaxf(dd,  1e-12f)) : 0.f;
  float nrm = dis_s * ew[e] * dis_d;
  int pos = offs[d] + atomicAdd(&cursor[d], 1);
  csr_src[pos] = s;
  csr_norm[pos] = nrm;
}

// ---------------- Kernel 5: one-hop propagation, XCD-locality + packed-f32 accumulate ---------
// tq = blockIdx.x % 8 (XCD-aligned band, L2-resident). Per edge: one b128/lane (uint4 = 8 bf16).
// Unpack u32 -> {lo<<16, hi&0xFFFF0000} (1 VALU/elem) and accumulate in f32x2 -> v_pk_fma_f32.
__global__ __launch_bounds__(256) void k_prop(
    const unsigned short* __restrict__ hin, unsigned short* __restrict__ hout,
    const int* __restrict__ offs, const int* __restrict__ csr_src,
    const float* __restrict__ csr_norm)
{
  const int bid = blockIdx.x;
  const int tq = bid & 7;                    // XCD-aligned t-quarter
  const int bgroup = bid >> 3;               // 0..499
  const int widx = threadIdx.x >> 6;
  const int lane = threadIdx.x & 63;
  const int b = bgroup * 4 + widx;           // 0..1999
  int beg = offs[b], end = offs[b + 1];      // both multiples of 4
  const size_t lelem = (size_t)(tq * 4 + (lane >> 4)) * 128 + (lane & 15) * 8;
  const uint4* hp = (const uint4*)hin;       // row stride 512 uint4
  const size_t lvec = lelem >> 3;

  f32x2 acc2[4] = {};
  for (int i = beg; i < end; i += 4) {
    int4   s4 = *(const int4*)&csr_src[i];
    float4 n4 = *(const float4*)&csr_norm[i];
    uint4 w0 = hp[(size_t)s4.x * 512 + lvec];
    uint4 w1 = hp[(size_t)s4.y * 512 + lvec];
    uint4 w2 = hp[(size_t)s4.z * 512 + lvec];
    uint4 w3 = hp[(size_t)s4.w * 512 + lvec];
    const unsigned ua[4][4] = {{w0.x, w0.y, w0.z, w0.w}, {w1.x, w1.y, w1.z, w1.w},
                               {w2.x, w2.y, w2.z, w2.w}, {w3.x, w3.y, w3.z, w3.w}};
    const float nm[4] = {n4.x, n4.y, n4.z, n4.w};
    #pragma unroll
    for (int e = 0; e < 4; ++e) {
      f32x2 nn; nn.x = nm[e]; nn.y = nm[e];
      #pragma unroll
      for (int p = 0; p < 4; ++p) {
        f32x2 f;
        f.x = __builtin_bit_cast(float, ua[e][p] << 16);
        f.y = __builtin_bit_cast(float, ua[e][p] & 0xFFFF0000u);
        acc2[p] += nn * f;
      }
    }
  }
  u16x8 o;
  #pragma unroll
  for (int p = 0; p < 4; ++p) {
    o[2 * p]     = f2bf(acc2[p].x);
    o[2 * p + 1] = f2bf(acc2[p].y);
  }
  *(u16x8*)&hout[(size_t)b * 4096 + lelem] = o;
}

// ---------------- Kernel 6: MFMA triple-GEMM (K=384) + epilogue, direct [b][c][t] store ---------
// Wave M-tile = 16 timesteps of ONE sample b; A-frags from x0/h1/h2 (4 each); cols 64 per chalf.
// Grid 1000 = 250 b-octs x {thalf, chalf}.
__global__ __launch_bounds__(512, 4) void k_gemm(
    const unsigned short* __restrict__ x0, const unsigned short* __restrict__ h1,
    const unsigned short* __restrict__ h2, const unsigned short* __restrict__ wB,
    const float* __restrict__ tb, float* __restrict__ out)
{
  __shared__ unsigned short sB[24576];   // 48KB: 64 cols x 384 K, fragment-ordered
  const int tid = threadIdx.x;
  const int w = tid >> 6, lane = tid & 63;
  const int sel = blockIdx.x / 250;                  // 0..3
  const int b = (blockIdx.x % 250) * 8 + w;
  const int thalf = sel & 1, chalf = sel >> 1;
  const int t0 = thalf * 16;
  const int r = lane & 15, q = lane >> 4;

  const size_t abase = ((size_t)b * 32 + t0 + r) * 128 + q * 8;
  bf16x8 a[12];
  #pragma unroll
  for (int ks = 0; ks < 12; ++ks) {
    const unsigned short* arr = (ks < 4) ? x0 : (ks < 8) ? h1 : h2;
    a[ks] = *(const bf16x8*)&arr[abase + (size_t)(ks & 3) * 32];
  }

  const float4* gB = (const float4*)(wB + (size_t)chalf * 24576);
  #pragma unroll
  for (int i = 0; i < 6; ++i) {
    int id = i * 512 + tid;
    ((float4*)sB)[id] = gB[id];
  }
  __syncthreads();

  f32x4 acc[4] = {};
  #pragma unroll
  for (int ks = 0; ks < 12; ++ks) {
    #pragma unroll
    for (int nf = 0; nf < 4; ++nf) {
      bf16x8 bv = *(const bf16x8*)&sB[((nf * 12 + ks) * 64 + lane) * 8];
      acc[nf] = __builtin_amdgcn_mfma_f32_16x16x32_bf16(a[ks], bv, acc[nf], 0, 0, 0);
    }
  }

  #pragma unroll
  for (int nf = 0; nf < 4; ++nf) {
    const int col = chalf * 64 + nf * 16 + r;
    const float bias = tb[col];
    float4 o;
    #pragma unroll
    for (int i = 0; i < 4; ++i) {
      const int t = t0 + q * 4 + i;
      float u = acc[nf][i] + bias;
      u = (u >= 0.f) ? u : NEG_S * u;
      float xv = bf2f(x0[((size_t)b * 32 + t) * 128 + col]);   // residual = xp
      ((float*)&o)[i] = xv + u;
    }
    *(float4*)&out[(size_t)b * 4096 + col * 32 + t0 + q * 4] = o;
  }
}

extern "C" void kernel_launch(void* const* d_in, const int* in_sizes, int n_in,
                              void* d_out, int out_size, void* d_ws, size_t ws_size,
                              hipStream_t stream)
{
  const float* x     = (const float*)d_in[0];
  const int*   ei    = (const int*)d_in[1];
  const float* ew    = (const float*)d_in[2];
  const float* cw    = (const float*)d_in[3];
  const float* cb    = (const float*)d_in[4];
  const float* gamma = (const float*)d_in[5];
  const float* beta  = (const float*)d_in[6];
  const float* tw    = (const float*)d_in[7];
  const float* tb    = (const float*)d_in[8];
  float* out = (float*)d_out;

  // workspace layout: three b-major feature arrays [b][32][128] bf16
  unsigned short* x0 = (unsigned short*)d_ws;                   // 64000*128 bf16
  unsigned short* h1 = x0 + (size_t)NNODE * 128;                // 64000*128 bf16
  unsigned short* h2 = h1 + (size_t)NNODE * 128;                // 64000*128 bf16
  float* deg = (float*)(h2 + (size_t)NNODE * 128);              // 2000 (16B aligned)
  int*   cnt    = (int*)(deg + B_N);                            // 2000
  int*   cursor = cnt + B_N;                                    // 2000
  int*   offs   = cursor + B_N;                                 // 2004 (padded for 16B align)
  int*   csr_src = offs + (B_N + 4);                            // EPAD_N
  float* csr_norm = (float*)(csr_src + EPAD_N);                 // EPAD_N
  unsigned short* wBc = (unsigned short*)(csr_norm + EPAD_N);   // 12288 bf16 frag-order
  unsigned short* wB  = wBc + 12288;                            // 49152 bf16 frag-order

  k_prep<<<96, 256, 0, stream>>>(cw, tw, wBc, wB, (int4*)deg);
  k_convln<<<500, 512, 0, stream>>>(x, wBc, cb, gamma, beta, x0);
  k_deg<<<(E_N + 255) / 256, 256, 0, stream>>>(ei, ew, deg, cnt);
  k_scan<<<1, 256, 0, stream>>>(cnt, offs);
  k_scatter<<<(E_N + 255) / 256, 256, 0, stream>>>(ei, ew, deg, offs, cursor, csr_src, csr_norm);
  k_prop<<<4000, 256, 0, stream>>>(x0, h1, offs, csr_src, csr_norm);
  k_prop<<<4000, 256, 0, stream>>>(h1, h2, offs, csr_src, csr_norm);
  k_gemm<<<1000, 512, 0, stream>>>(x0, h1, h2, wB, tb, out);
}

// Round 16
// 101.316 us; speedup vs baseline: 1.2349x; 1.0539x over previous
//
#include <hip/hip_runtime.h>
#include <hip/hip_bf16.h>
#include <math.h>

#define B_N   2000
#define T_N   32
#define CIN_N 32
#define COUT_N 128
#define E_N   32000
#define NEG_S 0.01f
#define EPS_S 1e-5f
#define NNODE (B_N * T_N)   // 64000
#define EPAD_N 38016        // padded CSR capacity (multiple-of-4 per node)
// contiguous meta region: deg(2000)+cnt(2000)+cursor(2000)+offs(2004)+csr_pk(38016)
#define META_I4 11505       // 46020 ints = 11505 int4

typedef __attribute__((ext_vector_type(8))) __bf16 bf16x8;
typedef __attribute__((ext_vector_type(4))) float f32x4;
typedef __attribute__((ext_vector_type(2))) float f32x2;
typedef __attribute__((ext_vector_type(8))) unsigned short u16x8;

__device__ __forceinline__ unsigned short f2bf(float f) {
  unsigned u = __builtin_bit_cast(unsigned, f);
  u += 0x7FFFu + ((u >> 16) & 1u);   // RNE (finite values)
  return (unsigned short)(u >> 16);
}
__device__ __forceinline__ float bf2f(unsigned short h) {
  unsigned u = ((unsigned)h) << 16;
  return __builtin_bit_cast(float, u);
}

// ---------------- Kernel P: fused prep — zero meta + cast both weight tensors ----------------
__global__ __launch_bounds__(256) void k_prep(
    const float* __restrict__ cw, const float* __restrict__ tw,
    unsigned short* __restrict__ wBc, unsigned short* __restrict__ wB,
    int4* __restrict__ meta)
{
  const int tid0 = blockIdx.x * 256 + threadIdx.x;
  const int stride = gridDim.x * 256;
  const int4 z = {0, 0, 0, 0};
  for (int i = tid0; i < META_I4; i += stride) meta[i] = z;
  for (int idx = tid0; idx < 12288; idx += stride) {
    int e = idx & 7, lane = (idx >> 3) & 63, rest = idx >> 9;
    int ks = rest % 3, nf2 = rest / 3;
    int col = nf2 * 16 + (lane & 15);
    int k = ks * 32 + ((lane >> 4) << 3) + e;
    wBc[idx] = f2bf(cw[col * 96 + k]);
  }
  for (int idx = tid0; idx < 49152; idx += stride) {
    int e = idx & 7, lane = (idx >> 3) & 63, rest = idx >> 9;
    int ks = rest % 12, nf2 = rest / 12;
    int col = nf2 * 16 + (lane & 15);
    int k = ks * 32 + ((lane >> 4) << 3) + e;
    wB[idx] = f2bf(tw[(k >> 7) * 16384 + (k & 127) * 128 + col]);
  }
}

// ---------------- Kernel 1: FUSED causal-conv (MFMA) + bias + LeakyReLU + LayerNorm ----------
// Block = 4 samples x 2 waves; wave = 16 timesteps (t0=0/16) x 128 cols of one sample b.
__global__ __launch_bounds__(512, 4) void k_convln(
    const float* __restrict__ x, const unsigned short* __restrict__ wBc,
    const float* __restrict__ cb, const float* __restrict__ gamma,
    const float* __restrict__ beta, unsigned short* __restrict__ x0)
{
  __shared__ unsigned short sB[12288];   // 24KB conv weights, frag-order
  __shared__ float sx4[4][1088];         // 17KB: per-sample im2col source, sx4[s][ci*34+t+2]
  __shared__ float red1[8], red2[8];
  const int tid = threadIdx.x;
  const int w = tid >> 6, lane = tid & 63;
  const int s = w >> 1;                       // sample slot 0..3
  const int b = blockIdx.x * 4 + s;
  const int t0 = (w & 1) * 16;
  const int r = lane & 15, q = lane >> 4;

  #pragma unroll
  for (int i = 0; i < 3; ++i) {
    int id = i * 512 + tid;                   // 1536 float4
    ((float4*)sB)[id] = ((const float4*)wBc)[id];
  }
  for (int idx = tid; idx < 4 * 1088; idx += 512) {
    int ss = idx / 1088;
    int rem = idx - ss * 1088;
    int ci = rem / 34, tt = rem - ci * 34;
    sx4[ss][rem] = (tt >= 2) ? x[(blockIdx.x * 4 + ss) * 1024 + ci * 32 + (tt - 2)] : 0.f;
  }
  __syncthreads();

  const int ta = t0 + r;
  u16x8 a_[3];
  #pragma unroll
  for (int ks = 0; ks < 3; ++ks) {
    #pragma unroll
    for (int e = 0; e < 8; ++e) {
      int k = ks * 32 + q * 8 + e;
      int ci = k / 3, kk = k - ci * 3;
      a_[ks][e] = f2bf(sx4[s][ci * 34 + ta + kk]);
    }
  }

  f32x4 acc[8] = {};
  #pragma unroll
  for (int ks = 0; ks < 3; ++ks) {
    bf16x8 a = __builtin_bit_cast(bf16x8, a_[ks]);
    #pragma unroll
    for (int nf = 0; nf < 8; ++nf) {
      bf16x8 bv = *(const bf16x8*)&sB[((nf * 3 + ks) * 64 + lane) * 8];
      acc[nf] = __builtin_amdgcn_mfma_f32_16x16x32_bf16(a, bv, acc[nf], 0, 0, 0);
    }
  }

  float s1 = 0.f, s2 = 0.f;
  #pragma unroll
  for (int nf = 0; nf < 8; ++nf) {
    const float bias = cb[nf * 16 + r];
    #pragma unroll
    for (int i = 0; i < 4; ++i) {
      float u = acc[nf][i] + bias;
      u = (u >= 0.f) ? u : NEG_S * u;
      acc[nf][i] = u;
      s1 += u; s2 += u * u;
    }
  }
  #pragma unroll
  for (int d = 32; d > 0; d >>= 1) {
    s1 += __shfl_down(s1, d);
    s2 += __shfl_down(s2, d);
  }
  if (lane == 0) { red1[w] = s1; red2[w] = s2; }
  __syncthreads();
  const float a1 = red1[w & ~1] + red1[w | 1];
  const float a2 = red2[w & ~1] + red2[w | 1];
  const float mu = a1 / 4096.f;
  const float rs = rsqrtf(a2 / 4096.f - mu * mu + EPS_S);

  #pragma unroll
  for (int nf = 0; nf < 8; ++nf) {
    const int col = nf * 16 + r;
    #pragma unroll
    for (int i = 0; i < 4; ++i) {
      const int t = t0 + q * 4 + i;
      float v = (acc[nf][i] - mu) * rs * gamma[col * 32 + t] + beta[col * 32 + t];
      x0[((size_t)b * 32 + t) * 128 + col] = f2bf(v);
    }
  }
}

// ---------------- Kernel 2: in-degree (weighted) + in-edge counts ----------------
__global__ void k_deg(const int* __restrict__ ei, const float* __restrict__ ew,
                      float* __restrict__ deg, int* __restrict__ cnt)
{
  int e = blockIdx.x * 256 + threadIdx.x;
  if (e >= E_N) return;
  int d = ei[E_N + e];
  atomicAdd(&deg[d], ew[e]);
  atomicAdd(&cnt[d], 1);
}

// ---------------- Kernel 3: single-block exclusive scan over 2000 PADDED counts ----------------
__global__ __launch_bounds__(256) void k_scan(const int* __restrict__ cnt, int* __restrict__ offs)
{
  __shared__ int wsum[4];
  int tid = threadIdx.x;
  int vals[8];
  int run = 0;
  #pragma unroll
  for (int i = 0; i < 8; ++i) {
    int idx = tid * 8 + i;
    vals[i] = run;
    int v = (idx < B_N) ? cnt[idx] : 0;
    v = (v + 3) & ~3;                       // pad to multiple of 4
    run += v;
  }
  int lane = tid & 63, wid = tid >> 6;
  int xs = run;
  #pragma unroll
  for (int d = 1; d < 64; d <<= 1) {
    int y = __shfl_up(xs, d);
    if (lane >= d) xs += y;
  }
  if (lane == 63) wsum[wid] = xs;
  __syncthreads();
  int pre = 0;
  for (int w = 0; w < wid; ++w) pre += wsum[w];
  int excl = pre + xs - run;
  #pragma unroll
  for (int i = 0; i < 8; ++i) {
    int idx = tid * 8 + i;
    if (idx <= B_N) offs[idx] = excl + vals[i];
  }
}

// ---------------- Kernel 4: CSR scatter + edge norm, PACKED {bf16 norm | u16 src} ------------
// Pad slots stay 0 -> src=0, norm=0 (exact no-op).
__global__ void k_scatter(const int* __restrict__ ei, const float* __restrict__ ew,
                          const float* __restrict__ deg, const int* __restrict__ offs,
                          int* __restrict__ cursor, unsigned* __restrict__ csr_pk)
{
  int e = blockIdx.x * 256 + threadIdx.x;
  if (e >= E_N) return;
  int s = ei[e], d = ei[E_N + e];
  float ds_ = deg[s], dd = deg[d];
  float dis_s = (ds_ > 0.f) ? rsqrtf(fmaxf(ds_, 1e-12f)) : 0.f;
  float dis_d = (dd  > 0.f) ? rsqrtf(fmaxf(dd,  1e-12f)) : 0.f;
  float nrm = dis_s * ew[e] * dis_d;
  int pos = offs[d] + atomicAdd(&cursor[d], 1);
  csr_pk[pos] = ((unsigned)f2bf(nrm) << 16) | (unsigned)s;
}

// ---------------- Kernel 5: one-hop propagation, XCD-locality + packed CSR -------------------
// tq = blockIdx.x % 8 (XCD-aligned band, L2-resident). Per 4 edges: ONE uint4 idx load
// + 4 b128 gathers (5 mem instrs vs 6). src = pk&0xFFFF, norm = bf16(pk>>16).
__global__ __launch_bounds__(256) void k_prop(
    const unsigned short* __restrict__ hin, unsigned short* __restrict__ hout,
    const int* __restrict__ offs, const unsigned* __restrict__ csr_pk)
{
  const int bid = blockIdx.x;
  const int tq = bid & 7;                    // XCD-aligned t-quarter
  const int bgroup = bid >> 3;               // 0..499
  const int widx = threadIdx.x >> 6;
  const int lane = threadIdx.x & 63;
  const int b = bgroup * 4 + widx;           // 0..1999
  int beg = offs[b], end = offs[b + 1];      // both multiples of 4
  const size_t lelem = (size_t)(tq * 4 + (lane >> 4)) * 128 + (lane & 15) * 8;
  const uint4* hp = (const uint4*)hin;       // row stride 512 uint4
  const size_t lvec = lelem >> 3;

  f32x2 acc2[4] = {};
  for (int i = beg; i < end; i += 4) {
    uint4 pk = *(const uint4*)&csr_pk[i];
    uint4 w0 = hp[(size_t)(pk.x & 0xFFFFu) * 512 + lvec];
    uint4 w1 = hp[(size_t)(pk.y & 0xFFFFu) * 512 + lvec];
    uint4 w2 = hp[(size_t)(pk.z & 0xFFFFu) * 512 + lvec];
    uint4 w3 = hp[(size_t)(pk.w & 0xFFFFu) * 512 + lvec];
    const unsigned ua[4][4] = {{w0.x, w0.y, w0.z, w0.w}, {w1.x, w1.y, w1.z, w1.w},
                               {w2.x, w2.y, w2.z, w2.w}, {w3.x, w3.y, w3.z, w3.w}};
    const float nm[4] = {__builtin_bit_cast(float, pk.x & 0xFFFF0000u),
                         __builtin_bit_cast(float, pk.y & 0xFFFF0000u),
                         __builtin_bit_cast(float, pk.z & 0xFFFF0000u),
                         __builtin_bit_cast(float, pk.w & 0xFFFF0000u)};
    #pragma unroll
    for (int e = 0; e < 4; ++e) {
      f32x2 nn; nn.x = nm[e]; nn.y = nm[e];
      #pragma unroll
      for (int p = 0; p < 4; ++p) {
        f32x2 f;
        f.x = __builtin_bit_cast(float, ua[e][p] << 16);
        f.y = __builtin_bit_cast(float, ua[e][p] & 0xFFFF0000u);
        acc2[p] += nn * f;
      }
    }
  }
  u16x8 o;
  #pragma unroll
  for (int p = 0; p < 4; ++p) {
    o[2 * p]     = f2bf(acc2[p].x);
    o[2 * p + 1] = f2bf(acc2[p].y);
  }
  *(u16x8*)&hout[(size_t)b * 4096 + lelem] = o;
}

// ---------------- Kernel 6: MFMA triple-GEMM (K=384), chalf-inner (A read ONCE) --------------
// Block = 8 waves = 8 b x 16 t (thalf); A-frags held in registers across both col-halves;
// sB (48KB) restaged per chalf with barriers. Grid 500 = 250 b-octs x thalf.
__global__ __launch_bounds__(512, 4) void k_gemm(
    const unsigned short* __restrict__ x0, const unsigned short* __restrict__ h1,
    const unsigned short* __restrict__ h2, const unsigned short* __restrict__ wB,
    const float* __restrict__ tb, float* __restrict__ out)
{
  __shared__ unsigned short sB[24576];   // 48KB: 64 cols x 384 K, fragment-ordered
  const int tid = threadIdx.x;
  const int w = tid >> 6, lane = tid & 63;
  const int thalf = blockIdx.x / 250;
  const int b = (blockIdx.x % 250) * 8 + w;
  const int t0 = thalf * 16;
  const int r = lane & 15, q = lane >> 4;

  // 12 A-fragments, read ONCE: ks 0..3 from x0, 4..7 from h1, 8..11 from h2
  const size_t abase = ((size_t)b * 32 + t0 + r) * 128 + q * 8;
  bf16x8 a[12];
  #pragma unroll
  for (int ks = 0; ks < 12; ++ks) {
    const unsigned short* arr = (ks < 4) ? x0 : (ks < 8) ? h1 : h2;
    a[ks] = *(const bf16x8*)&arr[abase + (size_t)(ks & 3) * 32];
  }

  for (int chalf = 0; chalf < 2; ++chalf) {
    if (chalf) __syncthreads();              // all waves done reading sB[chalf=0]
    const float4* gB = (const float4*)(wB + (size_t)chalf * 24576);
    #pragma unroll
    for (int i = 0; i < 6; ++i) {
      int id = i * 512 + tid;
      ((float4*)sB)[id] = gB[id];
    }
    __syncthreads();

    f32x4 acc[4] = {};
    #pragma unroll
    for (int ks = 0; ks < 12; ++ks) {
      #pragma unroll
      for (int nf = 0; nf < 4; ++nf) {
        bf16x8 bv = *(const bf16x8*)&sB[((nf * 12 + ks) * 64 + lane) * 8];
        acc[nf] = __builtin_amdgcn_mfma_f32_16x16x32_bf16(a[ks], bv, acc[nf], 0, 0, 0);
      }
    }

    #pragma unroll
    for (int nf = 0; nf < 4; ++nf) {
      const int col = chalf * 64 + nf * 16 + r;
      const float bias = tb[col];
      float4 o;
      #pragma unroll
      for (int i = 0; i < 4; ++i) {
        const int t = t0 + q * 4 + i;
        float u = acc[nf][i] + bias;
        u = (u >= 0.f) ? u : NEG_S * u;
        float xv = bf2f(x0[((size_t)b * 32 + t) * 128 + col]);   // residual = xp
        ((float*)&o)[i] = xv + u;
      }
      *(float4*)&out[(size_t)b * 4096 + col * 32 + t0 + q * 4] = o;
    }
  }
}

extern "C" void kernel_launch(void* const* d_in, const int* in_sizes, int n_in,
                              void* d_out, int out_size, void* d_ws, size_t ws_size,
                              hipStream_t stream)
{
  const float* x     = (const float*)d_in[0];
  const int*   ei    = (const int*)d_in[1];
  const float* ew    = (const float*)d_in[2];
  const float* cw    = (const float*)d_in[3];
  const float* cb    = (const float*)d_in[4];
  const float* gamma = (const float*)d_in[5];
  const float* beta  = (const float*)d_in[6];
  const float* tw    = (const float*)d_in[7];
  const float* tb    = (const float*)d_in[8];
  float* out = (float*)d_out;

  // workspace layout: three b-major feature arrays [b][32][128] bf16
  unsigned short* x0 = (unsigned short*)d_ws;                   // 64000*128 bf16
  unsigned short* h1 = x0 + (size_t)NNODE * 128;                // 64000*128 bf16
  unsigned short* h2 = h1 + (size_t)NNODE * 128;                // 64000*128 bf16
  float* deg = (float*)(h2 + (size_t)NNODE * 128);              // 2000 (16B aligned)
  int*   cnt    = (int*)(deg + B_N);                            // 2000
  int*   cursor = cnt + B_N;                                    // 2000
  int*   offs   = cursor + B_N;                                 // 2004 (padded for 16B align)
  unsigned* csr_pk = (unsigned*)(offs + (B_N + 4));             // EPAD_N packed {bf16 norm|u16 src}
  unsigned short* wBc = (unsigned short*)(csr_pk + EPAD_N);     // 12288 bf16 frag-order
  unsigned short* wB  = wBc + 12288;                            // 49152 bf16 frag-order

  k_prep<<<96, 256, 0, stream>>>(cw, tw, wBc, wB, (int4*)deg);
  k_convln<<<500, 512, 0, stream>>>(x, wBc, cb, gamma, beta, x0);
  k_deg<<<(E_N + 255) / 256, 256, 0, stream>>>(ei, ew, deg, cnt);
  k_scan<<<1, 256, 0, stream>>>(cnt, offs);
  k_scatter<<<(E_N + 255) / 256, 256, 0, stream>>>(ei, ew, deg, offs, cursor, csr_pk);
  k_prop<<<4000, 256, 0, stream>>>(x0, h1, offs, csr_pk);
  k_prop<<<4000, 256, 0, stream>>>(h1, h2, offs, csr_pk);
  k_gemm<<<500, 512, 0, stream>>>(x0, h1, h2, wB, tb, out);
}

// Round 17
// 87.825 us; speedup vs baseline: 1.4246x; 1.1536x over previous
//
#include <hip/hip_runtime.h>
#include <hip/hip_bf16.h>
#include <math.h>

#define B_N   2000
#define T_N   32
#define CIN_N 32
#define COUT_N 128
#define E_N   32000
#define NEG_S 0.01f
#define EPS_S 1e-5f
#define NNODE (B_N * T_N)   // 64000
#define EPAD_N 38016        // padded CSR capacity (multiple-of-4 per node)
// contiguous meta region: deg(2000)+cnt(2000)+cursor(2000)+offs(2004)+csr_pk(38016)
#define META_I4 11505       // 46020 ints = 11505 int4

typedef __attribute__((ext_vector_type(8))) __bf16 bf16x8;
typedef __attribute__((ext_vector_type(4))) float f32x4;
typedef __attribute__((ext_vector_type(2))) float f32x2;
typedef __attribute__((ext_vector_type(8))) unsigned short u16x8;

__device__ __forceinline__ unsigned short f2bf(float f) {
  unsigned u = __builtin_bit_cast(unsigned, f);
  u += 0x7FFFu + ((u >> 16) & 1u);   // RNE (finite values)
  return (unsigned short)(u >> 16);
}
__device__ __forceinline__ float bf2f(unsigned short h) {
  unsigned u = ((unsigned)h) << 16;
  return __builtin_bit_cast(float, u);
}

// ---------------- Kernel P: fused prep — zero meta + cast both weight tensors ----------------
__global__ __launch_bounds__(256) void k_prep(
    const float* __restrict__ cw, const float* __restrict__ tw,
    unsigned short* __restrict__ wBc, unsigned short* __restrict__ wB,
    int4* __restrict__ meta)
{
  const int tid0 = blockIdx.x * 256 + threadIdx.x;
  const int stride = gridDim.x * 256;
  const int4 z = {0, 0, 0, 0};
  for (int i = tid0; i < META_I4; i += stride) meta[i] = z;
  for (int idx = tid0; idx < 12288; idx += stride) {
    int e = idx & 7, lane = (idx >> 3) & 63, rest = idx >> 9;
    int ks = rest % 3, nf2 = rest / 3;
    int col = nf2 * 16 + (lane & 15);
    int k = ks * 32 + ((lane >> 4) << 3) + e;
    wBc[idx] = f2bf(cw[col * 96 + k]);
  }
  for (int idx = tid0; idx < 49152; idx += stride) {
    int e = idx & 7, lane = (idx >> 3) & 63, rest = idx >> 9;
    int ks = rest % 12, nf2 = rest / 12;
    int col = nf2 * 16 + (lane & 15);
    int k = ks * 32 + ((lane >> 4) << 3) + e;
    wB[idx] = f2bf(tw[(k >> 7) * 16384 + (k & 127) * 128 + col]);
  }
}

// ---------------- Kernel 1: FUSED conv+LN, PLUS grid-strided degree histogram ----------------
// Runs after k_prep (meta zeroed at kernel boundary) -> deg/cnt atomics are safe here.
// Block = 4 samples x 2 waves; wave = 16 timesteps (t0=0/16) x 128 cols of one sample b.
__global__ __launch_bounds__(512, 4) void k_convln(
    const float* __restrict__ x, const unsigned short* __restrict__ wBc,
    const float* __restrict__ cb, const float* __restrict__ gamma,
    const float* __restrict__ beta, unsigned short* __restrict__ x0,
    const int* __restrict__ ei, const float* __restrict__ ew,
    float* __restrict__ deg, int* __restrict__ cnt)
{
  __shared__ unsigned short sB[12288];   // 24KB conv weights, frag-order
  __shared__ float sx4[4][1088];         // 17KB: per-sample im2col source, sx4[s][ci*34+t+2]
  __shared__ float red1[8], red2[8];
  const int tid = threadIdx.x;

  // fused in-degree histogram (500*512 threads cover 32000 edges)
  const int eg = blockIdx.x * 512 + tid;
  if (eg < E_N) {
    int d = ei[E_N + eg];
    atomicAdd(&deg[d], ew[eg]);
    atomicAdd(&cnt[d], 1);
  }

  const int w = tid >> 6, lane = tid & 63;
  const int s = w >> 1;                       // sample slot 0..3
  const int b = blockIdx.x * 4 + s;
  const int t0 = (w & 1) * 16;
  const int r = lane & 15, q = lane >> 4;

  #pragma unroll
  for (int i = 0; i < 3; ++i) {
    int id = i * 512 + tid;                   // 1536 float4
    ((float4*)sB)[id] = ((const float4*)wBc)[id];
  }
  for (int idx = tid; idx < 4 * 1088; idx += 512) {
    int ss = idx / 1088;
    int rem = idx - ss * 1088;
    int ci = rem / 34, tt = rem - ci * 34;
    sx4[ss][rem] = (tt >= 2) ? x[(blockIdx.x * 4 + ss) * 1024 + ci * 32 + (tt - 2)] : 0.f;
  }
  __syncthreads();

  const int ta = t0 + r;
  u16x8 a_[3];
  #pragma unroll
  for (int ks = 0; ks < 3; ++ks) {
    #pragma unroll
    for (int e = 0; e < 8; ++e) {
      int k = ks * 32 + q * 8 + e;
      int ci = k / 3, kk = k - ci * 3;
      a_[ks][e] = f2bf(sx4[s][ci * 34 + ta + kk]);
    }
  }

  f32x4 acc[8] = {};
  #pragma unroll
  for (int ks = 0; ks < 3; ++ks) {
    bf16x8 a = __builtin_bit_cast(bf16x8, a_[ks]);
    #pragma unroll
    for (int nf = 0; nf < 8; ++nf) {
      bf16x8 bv = *(const bf16x8*)&sB[((nf * 3 + ks) * 64 + lane) * 8];
      acc[nf] = __builtin_amdgcn_mfma_f32_16x16x32_bf16(a, bv, acc[nf], 0, 0, 0);
    }
  }

  float s1 = 0.f, s2 = 0.f;
  #pragma unroll
  for (int nf = 0; nf < 8; ++nf) {
    const float bias = cb[nf * 16 + r];
    #pragma unroll
    for (int i = 0; i < 4; ++i) {
      float u = acc[nf][i] + bias;
      u = (u >= 0.f) ? u : NEG_S * u;
      acc[nf][i] = u;
      s1 += u; s2 += u * u;
    }
  }
  #pragma unroll
  for (int d = 32; d > 0; d >>= 1) {
    s1 += __shfl_down(s1, d);
    s2 += __shfl_down(s2, d);
  }
  if (lane == 0) { red1[w] = s1; red2[w] = s2; }
  __syncthreads();
  const float a1 = red1[w & ~1] + red1[w | 1];
  const float a2 = red2[w & ~1] + red2[w | 1];
  const float mu = a1 / 4096.f;
  const float rs = rsqrtf(a2 / 4096.f - mu * mu + EPS_S);

  #pragma unroll
  for (int nf = 0; nf < 8; ++nf) {
    const int col = nf * 16 + r;
    #pragma unroll
    for (int i = 0; i < 4; ++i) {
      const int t = t0 + q * 4 + i;
      float v = (acc[nf][i] - mu) * rs * gamma[col * 32 + t] + beta[col * 32 + t];
      x0[((size_t)b * 32 + t) * 128 + col] = f2bf(v);
    }
  }
}

// ---------------- Kernel 4: FUSED scan+scatter — each block scans cnt in LDS ----------------
// Redundant per-block padded exclusive scan (2000 entries, cheap) kills the k_scan dispatch.
// Block 0 publishes offs to global (needed by k_prop, a later kernel). Pads stay 0.
__global__ __launch_bounds__(256) void k_scatterscan(
    const int* __restrict__ ei, const float* __restrict__ ew,
    const float* __restrict__ deg, const int* __restrict__ cnt,
    int* __restrict__ cursor, int* __restrict__ offs, unsigned* __restrict__ csr_pk)
{
  __shared__ int soffs[2004];
  __shared__ int wsum[4];
  const int tid = threadIdx.x;
  int vals[8];
  int run = 0;
  #pragma unroll
  for (int i = 0; i < 8; ++i) {
    int idx = tid * 8 + i;
    vals[i] = run;
    int v = (idx < B_N) ? cnt[idx] : 0;
    v = (v + 3) & ~3;                       // pad to multiple of 4
    run += v;
  }
  const int lane = tid & 63, wid = tid >> 6;
  int xs = run;
  #pragma unroll
  for (int d = 1; d < 64; d <<= 1) {
    int y = __shfl_up(xs, d);
    if (lane >= d) xs += y;
  }
  if (lane == 63) wsum[wid] = xs;
  __syncthreads();
  int pre = 0;
  for (int w = 0; w < wid; ++w) pre += wsum[w];
  int excl = pre + xs - run;
  #pragma unroll
  for (int i = 0; i < 8; ++i) {
    int idx = tid * 8 + i;
    if (idx <= B_N) soffs[idx] = excl + vals[i];
  }
  __syncthreads();
  if (blockIdx.x == 0) {
    for (int idx = tid; idx <= B_N; idx += 256) offs[idx] = soffs[idx];
  }

  int e = blockIdx.x * 256 + tid;
  if (e >= E_N) return;
  int s = ei[e], d = ei[E_N + e];
  float ds_ = deg[s], dd = deg[d];
  float dis_s = (ds_ > 0.f) ? rsqrtf(fmaxf(ds_, 1e-12f)) : 0.f;
  float dis_d = (dd  > 0.f) ? rsqrtf(fmaxf(dd,  1e-12f)) : 0.f;
  float nrm = dis_s * ew[e] * dis_d;
  int pos = soffs[d] + atomicAdd(&cursor[d], 1);
  csr_pk[pos] = ((unsigned)f2bf(nrm) << 16) | (unsigned)s;
}

// ---------------- Kernel 5: one-hop propagation, XCD-locality + scalarized CSR ---------------
// tq = blockIdx.x % 8 (XCD-aligned band, L2-resident). b forced wave-uniform via readfirstlane
// -> offs/csr_pk reads become s_load (scalar pipe), vmem pipe carries only the 4 gathers/iter.
__global__ __launch_bounds__(256) void k_prop(
    const unsigned short* __restrict__ hin, unsigned short* __restrict__ hout,
    const int* __restrict__ offs, const unsigned* __restrict__ csr_pk)
{
  const int bid = blockIdx.x;
  const int tq = bid & 7;                    // XCD-aligned t-quarter
  const int bgroup = bid >> 3;               // 0..499
  const int widx = threadIdx.x >> 6;
  const int lane = threadIdx.x & 63;
  const int b = __builtin_amdgcn_readfirstlane(bgroup * 4 + widx);   // wave-uniform SGPR
  const int beg = offs[b], end = offs[b + 1];                        // s_load
  const size_t lelem = (size_t)(tq * 4 + (lane >> 4)) * 128 + (lane & 15) * 8;
  const uint4* hp = (const uint4*)hin;       // row stride 512 uint4
  const size_t lvec = lelem >> 3;

  f32x2 acc2[4] = {};
  for (int i = beg; i < end; i += 4) {
    uint4 pk = *(const uint4*)&csr_pk[i];    // uniform -> s_load_dwordx4
    uint4 w0 = hp[(size_t)(pk.x & 0xFFFFu) * 512 + lvec];
    uint4 w1 = hp[(size_t)(pk.y & 0xFFFFu) * 512 + lvec];
    uint4 w2 = hp[(size_t)(pk.z & 0xFFFFu) * 512 + lvec];
    uint4 w3 = hp[(size_t)(pk.w & 0xFFFFu) * 512 + lvec];
    const unsigned ua[4][4] = {{w0.x, w0.y, w0.z, w0.w}, {w1.x, w1.y, w1.z, w1.w},
                               {w2.x, w2.y, w2.z, w2.w}, {w3.x, w3.y, w3.z, w3.w}};
    const float nm[4] = {__builtin_bit_cast(float, pk.x & 0xFFFF0000u),
                         __builtin_bit_cast(float, pk.y & 0xFFFF0000u),
                         __builtin_bit_cast(float, pk.z & 0xFFFF0000u),
                         __builtin_bit_cast(float, pk.w & 0xFFFF0000u)};
    #pragma unroll
    for (int e = 0; e < 4; ++e) {
      f32x2 nn; nn.x = nm[e]; nn.y = nm[e];
      #pragma unroll
      for (int p = 0; p < 4; ++p) {
        f32x2 f;
        f.x = __builtin_bit_cast(float, ua[e][p] << 16);
        f.y = __builtin_bit_cast(float, ua[e][p] & 0xFFFF0000u);
        acc2[p] += nn * f;
      }
    }
  }
  u16x8 o;
  #pragma unroll
  for (int p = 0; p < 4; ++p) {
    o[2 * p]     = f2bf(acc2[p].x);
    o[2 * p + 1] = f2bf(acc2[p].y);
  }
  *(u16x8*)&hout[(size_t)b * 4096 + lelem] = o;
}

// ---------------- Kernel 6: MFMA triple-GEMM (K=384), chalf-inner (A read ONCE) --------------
// Block = 8 waves = 8 b x 16 t (thalf); A-frags held in registers across both col-halves;
// sB (48KB) restaged per chalf with barriers. Grid 500 = 250 b-octs x thalf.
__global__ __launch_bounds__(512, 4) void k_gemm(
    const unsigned short* __restrict__ x0, const unsigned short* __restrict__ h1,
    const unsigned short* __restrict__ h2, const unsigned short* __restrict__ wB,
    const float* __restrict__ tb, float* __restrict__ out)
{
  __shared__ unsigned short sB[24576];   // 48KB: 64 cols x 384 K, fragment-ordered
  const int tid = threadIdx.x;
  const int w = tid >> 6, lane = tid & 63;
  const int thalf = blockIdx.x / 250;
  const int b = (blockIdx.x % 250) * 8 + w;
  const int t0 = thalf * 16;
  const int r = lane & 15, q = lane >> 4;

  const size_t abase = ((size_t)b * 32 + t0 + r) * 128 + q * 8;
  bf16x8 a[12];
  #pragma unroll
  for (int ks = 0; ks < 12; ++ks) {
    const unsigned short* arr = (ks < 4) ? x0 : (ks < 8) ? h1 : h2;
    a[ks] = *(const bf16x8*)&arr[abase + (size_t)(ks & 3) * 32];
  }

  for (int chalf = 0; chalf < 2; ++chalf) {
    if (chalf) __syncthreads();              // all waves done reading sB[chalf=0]
    const float4* gB = (const float4*)(wB + (size_t)chalf * 24576);
    #pragma unroll
    for (int i = 0; i < 6; ++i) {
      int id = i * 512 + tid;
      ((float4*)sB)[id] = gB[id];
    }
    __syncthreads();

    f32x4 acc[4] = {};
    #pragma unroll
    for (int ks = 0; ks < 12; ++ks) {
      #pragma unroll
      for (int nf = 0; nf < 4; ++nf) {
        bf16x8 bv = *(const bf16x8*)&sB[((nf * 12 + ks) * 64 + lane) * 8];
        acc[nf] = __builtin_amdgcn_mfma_f32_16x16x32_bf16(a[ks], bv, acc[nf], 0, 0, 0);
      }
    }

    #pragma unroll
    for (int nf = 0; nf < 4; ++nf) {
      const int col = chalf * 64 + nf * 16 + r;
      const float bias = tb[col];
      float4 o;
      #pragma unroll
      for (int i = 0; i < 4; ++i) {
        const int t = t0 + q * 4 + i;
        float u = acc[nf][i] + bias;
        u = (u >= 0.f) ? u : NEG_S * u;
        float xv = bf2f(x0[((size_t)b * 32 + t) * 128 + col]);   // residual = xp
        ((float*)&o)[i] = xv + u;
      }
      *(float4*)&out[(size_t)b * 4096 + col * 32 + t0 + q * 4] = o;
    }
  }
}

extern "C" void kernel_launch(void* const* d_in, const int* in_sizes, int n_in,
                              void* d_out, int out_size, void* d_ws, size_t ws_size,
                              hipStream_t stream)
{
  const float* x     = (const float*)d_in[0];
  const int*   ei    = (const int*)d_in[1];
  const float* ew    = (const float*)d_in[2];
  const float* cw    = (const float*)d_in[3];
  const float* cb    = (const float*)d_in[4];
  const float* gamma = (const float*)d_in[5];
  const float* beta  = (const float*)d_in[6];
  const float* tw    = (const float*)d_in[7];
  const float* tb    = (const float*)d_in[8];
  float* out = (float*)d_out;

  // workspace layout: three b-major feature arrays [b][32][128] bf16
  unsigned short* x0 = (unsigned short*)d_ws;                   // 64000*128 bf16
  unsigned short* h1 = x0 + (size_t)NNODE * 128;                // 64000*128 bf16
  unsigned short* h2 = h1 + (size_t)NNODE * 128;                // 64000*128 bf16
  float* deg = (float*)(h2 + (size_t)NNODE * 128);              // 2000 (16B aligned)
  int*   cnt    = (int*)(deg + B_N);                            // 2000
  int*   cursor = cnt + B_N;                                    // 2000
  int*   offs   = cursor + B_N;                                 // 2004 (padded for 16B align)
  unsigned* csr_pk = (unsigned*)(offs + (B_N + 4));             // EPAD_N packed {bf16 norm|u16 src}
  unsigned short* wBc = (unsigned short*)(csr_pk + EPAD_N);     // 12288 bf16 frag-order
  unsigned short* wB  = wBc + 12288;                            // 49152 bf16 frag-order

  k_prep<<<96, 256, 0, stream>>>(cw, tw, wBc, wB, (int4*)deg);
  k_convln<<<500, 512, 0, stream>>>(x, wBc, cb, gamma, beta, x0, ei, ew, deg, cnt);
  k_scatterscan<<<125, 256, 0, stream>>>(ei, ew, deg, cnt, cursor, offs, csr_pk);
  k_prop<<<4000, 256, 0, stream>>>(x0, h1, offs, csr_pk);
  k_prop<<<4000, 256, 0, stream>>>(h1, h2, offs, csr_pk);
  k_gemm<<<500, 512, 0, stream>>>(x0, h1, h2, wB, tb, out);
}